// Round 5
// baseline (220.788 us; speedup 1.0000x reference)
//
#include <hip/hip_runtime.h>

// Problem: out[b] = weight[layer_ids[b]] @ z[b] + bias[layer_ids[b]]
// All fp32 (layer_ids int32). z[4096,1024], weight[16,1024,1024],
// bias[16,1024], out[4096,1024].
//
// R10: barrier-free direct-register GEMM.
//  R9 diagnosis: ~70% stall. Only ~2 live waves/SIMD (grid has ~560 live
//  blocks) and 2 barriers/K-step serialize every wave on the slowest
//  vmcnt drain; plus the 2-deep prefetch spilled to scratch
//  (WRITE_SIZE 16.4->29.2 MB).
//  Fix: drop LDS staging entirely. Each wave loads its own A/B fragments
//  straight from global (L1 serves intra-block reuse: 16 KB/step working
//  set < 32 KB L1), converts f32->f16 in-register (A = exact hi/lo split,
//  B = single RTN plane; same numerics as R9, absmax 0.03125 passed),
//  and runs the whole K-loop with ZERO barriers -> compiler freely
//  software-pipelines loads one iteration ahead per wave.
//  LDS holds only the 64-entry permTile. XCD-pinned layer placement kept.

#define HDIM 1024
#define LNUM 16
#define BTOT 4096

constexpr int BM = 64, BN = 128, BK = 32;
constexpr int NT = HDIM / BK;   // 32 K-steps
constexpr int MSLOTS = 8;       // m-slots per layer in grid (strip-mined past)

typedef __attribute__((ext_vector_type(4))) float floatx4;
typedef __attribute__((ext_vector_type(2))) __fp16 cvt16x2;   // cvt_pkrtz result
typedef __attribute__((ext_vector_type(8))) _Float16 f16x8;   // MFMA fragment
typedef __attribute__((ext_vector_type(2))) unsigned int uintx2;
typedef __attribute__((ext_vector_type(4))) unsigned int uintx4;

// Exact split of 4 f32 into packed f16 hi + lo words (v = hi + lo).
__device__ __forceinline__ void split4(floatx4 v, uintx2& hw, uintx2& lw) {
    cvt16x2 h01 = __builtin_amdgcn_cvt_pkrtz(v[0], v[1]);
    cvt16x2 h23 = __builtin_amdgcn_cvt_pkrtz(v[2], v[3]);
    cvt16x2 l01 = __builtin_amdgcn_cvt_pkrtz(v[0] - (float)h01[0],
                                             v[1] - (float)h01[1]);
    cvt16x2 l23 = __builtin_amdgcn_cvt_pkrtz(v[2] - (float)h23[0],
                                             v[3] - (float)h23[1]);
    hw[0] = __builtin_bit_cast(unsigned int, h01);
    hw[1] = __builtin_bit_cast(unsigned int, h23);
    lw[0] = __builtin_bit_cast(unsigned int, l01);
    lw[1] = __builtin_bit_cast(unsigned int, l23);
}

// 8 f32 (two floatx4) -> hi/lo f16x8 fragments.
__device__ __forceinline__ void split8(floatx4 v0, floatx4 v1,
                                       f16x8& hi, f16x8& lo) {
    uintx2 h0, l0, h1, l1;
    split4(v0, h0, l0);
    split4(v1, h1, l1);
    uintx4 h = {h0[0], h0[1], h1[0], h1[1]};
    uintx4 l = {l0[0], l0[1], l1[0], l1[1]};
    hi = __builtin_bit_cast(f16x8, h);
    lo = __builtin_bit_cast(f16x8, l);
}

// 8 f32 -> single RTN f16x8 (v_cvt_f16_f32 default round-nearest-even).
__device__ __forceinline__ f16x8 cvt8_rtn(floatx4 v0, floatx4 v1) {
    unsigned u0 = (unsigned)__builtin_bit_cast(unsigned short, (_Float16)v0[0])
                | ((unsigned)__builtin_bit_cast(unsigned short, (_Float16)v0[1]) << 16);
    unsigned u1 = (unsigned)__builtin_bit_cast(unsigned short, (_Float16)v0[2])
                | ((unsigned)__builtin_bit_cast(unsigned short, (_Float16)v0[3]) << 16);
    unsigned u2 = (unsigned)__builtin_bit_cast(unsigned short, (_Float16)v1[0])
                | ((unsigned)__builtin_bit_cast(unsigned short, (_Float16)v1[1]) << 16);
    unsigned u3 = (unsigned)__builtin_bit_cast(unsigned short, (_Float16)v1[2])
                | ((unsigned)__builtin_bit_cast(unsigned short, (_Float16)v1[3]) << 16);
    uintx4 u = {u0, u1, u2, u3};
    return __builtin_bit_cast(f16x8, u);
}

__global__ __launch_bounds__(256, 2) void fused_direct_mfma_kernel(
    const float* __restrict__ z,
    const int* __restrict__ layer_ids,
    const float* __restrict__ weight,
    const float* __restrict__ bias,
    float* __restrict__ out) {

    // Grid: 1024 blocks = 8 XCD x {2 layer-halves x 8 m-slots x 8 n-blocks}.
    // bid&7 pins layer l to an XCD so its 4MB weight panel stays in one L2.
    const int bid  = blockIdx.x;
    const int xcd  = bid & 7;
    const int slot = bid >> 3;                 // 0..127
    const int l    = xcd + ((slot >> 6) << 3); // 0..15
    const int rem  = slot & 63;
    const int my   = rem >> 3;                 // m-slot 0..7
    const int nx   = rem & 7;                  // n-block 0..7
    const int n0   = nx * BN;

    const int tid  = threadIdx.x;
    const int lane = tid & 63;
    const int w    = tid >> 6;                 // wave 0..3
    const int wm   = w & 1;                    // wave m-slot (rows wm*32..+31)
    const int wn   = w >> 1;                   // wave n-slot (cols wn*64..+63)

    __shared__ int permTile[BM];
    __shared__ int waveSums[4];

    // ---- fused grouping scan (rank of each matching b among layer-l rows) ----
    const int4* lid4 = (const int4*)layer_ids;
    unsigned mask = 0;
#pragma unroll
    for (int q = 0; q < 4; ++q) {
        int4 v = lid4[tid * 4 + q];
        mask |= (unsigned)(v.x == l) << (4 * q)
             |  (unsigned)(v.y == l) << (4 * q + 1)
             |  (unsigned)(v.z == l) << (4 * q + 2)
             |  (unsigned)(v.w == l) << (4 * q + 3);
    }
    const int ct = __popc(mask);
    int x = ct;                                // wave-inclusive scan of ct
#pragma unroll
    for (int o = 1; o < 64; o <<= 1) {
        int v = __shfl_up(x, o);
        if (lane >= o) x += v;
    }
    if (lane == 63) waveSums[w] = x;
    __syncthreads();
    int waveBase = 0, cnt = 0;
#pragma unroll
    for (int w2 = 0; w2 < 4; ++w2) {
        int s = waveSums[w2];
        if (w2 < w) waveBase += s;
        cnt += s;
    }
    const int et = waveBase + x - ct;          // exclusive rank of 1st match

    // ---- per-lane fragment coordinates ----
    const int lr = lane & 15;                  // row (A) / col (B) within tile
    const int ks = lane >> 4;                  // k-slab: elems ks*8..ks*8+7
    const float* wBase = weight + (size_t)l * HDIM * HDIM;

    // B row pointers: constant across m0 iterations.
    const float* bRow[4];
#pragma unroll
    for (int j = 0; j < 4; ++j)
        bRow[j] = wBase + (size_t)(n0 + wn * 64 + j * 16 + lr) * HDIM + ks * 8;

    const int colBase = n0 + wn * 64 + lr;
    float bb[4];
#pragma unroll
    for (int j = 0; j < 4; ++j) bb[j] = bias[l * HDIM + colBase + j * 16];

    // ---- strip-mine m0 (single iteration for cnt <= 512, the normal case) ----
    for (int m0 = my * BM; m0 < cnt; m0 += MSLOTS * BM) {
        __syncthreads();                       // permTile reuse guard
        {
            unsigned m2 = mask;
            int r = et;
            while (m2) {
                int p = __ffs(m2) - 1;
                m2 &= m2 - 1;
                unsigned rr = (unsigned)(r - m0);
                if (rr < (unsigned)BM) permTile[rr] = tid * 16 + p;
                ++r;
            }
        }
        __syncthreads();

        // A row pointers for this strip (per-lane gather via permTile).
        const float* aRow[2];
#pragma unroll
        for (int i = 0; i < 2; ++i) {
            int gm = wm * 32 + i * 16 + lr;    // tile-local row
            if (gm > cnt - 1 - m0) gm = cnt - 1 - m0;   // clamp (stores guarded)
            aRow[i] = z + (size_t)permTile[gm] * HDIM + ks * 8;
        }

        floatx4 acc[2][4] = {};
        floatx4 av[2][2], bv[4][2];

        auto loadT = [&](int k0) {
#pragma unroll
            for (int i = 0; i < 2; ++i) {
                av[i][0] = *(const floatx4*)(aRow[i] + k0);
                av[i][1] = *(const floatx4*)(aRow[i] + k0 + 4);
            }
#pragma unroll
            for (int j = 0; j < 4; ++j) {
                bv[j][0] = *(const floatx4*)(bRow[j] + k0);
                bv[j][1] = *(const floatx4*)(bRow[j] + k0 + 4);
            }
        };

        loadT(0);

#pragma unroll 2
        for (int t = 0; t < NT; ++t) {
            // Convert current step's registers to MFMA fragments.
            f16x8 ah[2], al[2], bh[4];
#pragma unroll
            for (int i = 0; i < 2; ++i) split8(av[i][0], av[i][1], ah[i], al[i]);
#pragma unroll
            for (int j = 0; j < 4; ++j) bh[j] = cvt8_rtn(bv[j][0], bv[j][1]);

            // Issue next step's loads (1 iteration ahead; no barriers anywhere).
            if (t + 1 < NT) loadT((t + 1) * BK);

            // 16 MFMAs: pass 1 (hi), then pass 2 (lo) — 8 instrs between
            // touches of the same accumulator.
#pragma unroll
            for (int i = 0; i < 2; ++i)
#pragma unroll
                for (int j = 0; j < 4; ++j)
                    acc[i][j] = __builtin_amdgcn_mfma_f32_16x16x32_f16(
                        ah[i], bh[j], acc[i][j], 0, 0, 0);
#pragma unroll
            for (int i = 0; i < 2; ++i)
#pragma unroll
                for (int j = 0; j < 4; ++j)
                    acc[i][j] = __builtin_amdgcn_mfma_f32_16x16x32_f16(
                        al[i], bh[j], acc[i][j], 0, 0, 0);
        }

        // Epilogue: C/D layout col=lane&15, row=(lane>>4)*4+reg (m89-verified).
        const int rq = lane >> 4;
#pragma unroll
        for (int i = 0; i < 2; ++i) {
#pragma unroll
            for (int v = 0; v < 4; ++v) {
                int gm = wm * 32 + i * 16 + rq * 4 + v;   // tile-local row
                if (m0 + gm < cnt) {
                    float* o = out + (size_t)permTile[gm] * HDIM + colBase;
#pragma unroll
                    for (int j = 0; j < 4; ++j) o[j * 16] = acc[i][j][v] + bb[j];
                }
            }
        }
    }
}

extern "C" void kernel_launch(void* const* d_in, const int* in_sizes, int n_in,
                              void* d_out, int out_size, void* d_ws, size_t ws_size,
                              hipStream_t stream) {
    // Order-proof pointer resolution (sizes disambiguate).
    const float* z = nullptr;
    const int* layer_ids = nullptr;
    const float* weight = nullptr;
    const float* bias = nullptr;
    for (int i = 0; i < n_in; ++i) {
        switch (in_sizes[i]) {
            case BTOT * HDIM:        z = (const float*)d_in[i]; break;
            case BTOT:               layer_ids = (const int*)d_in[i]; break;
            case LNUM * HDIM * HDIM: weight = (const float*)d_in[i]; break;
            case LNUM * HDIM:        bias = (const float*)d_in[i]; break;
        }
    }
    float* out = (float*)d_out;

    // Single dispatch: 8 XCD x 2 layer-halves x 8 m-slots x 8 n-blocks = 1024.
    fused_direct_mfma_kernel<<<dim3(1024), 256, 0, stream>>>(
        z, layer_ids, weight, bias, out);
}

// Round 7
// 135.580 us; speedup vs baseline: 1.6285x; 1.6285x over previous
//
#include <hip/hip_runtime.h>

// Problem: out[b] = weight[layer_ids[b]] @ z[b] + bias[layer_ids[b]]
// All fp32 (layer_ids int32). z[4096,1024], weight[16,1024,1024],
// bias[16,1024], out[4096,1024].
//
// R12 = R11 resubmitted (round 6 failed on infra, not kernel).
// R11: fix the vmcnt stall in the LDS-staged schedule without spilling.
//  R10 showed direct-reg loads are 2.3x worse (scattered 16-row dwordx4,
//  nothing hides latency at 2 waves/SIMD) -> LDS staging restored.
//  R9's stall: stage's ds_write waited vmcnt(0) on loads issued ~100cy
//  earlier; its 2-reg-set fix spilled (WRITE_SIZE +12.8MB).
//  R11 schedule per K-step:   stage(t+1)  [regs loaded a FULL iteration ago]
//                             issue loads(t+2) [reuse same regs after write]
//                             compute(t)
//                             barrier
//  Single 24-reg prefetch set, 2-deep in time. Register-destined
//  global_loads survive s_barrier (only LDS-destined ops get drained).
//  Numerics: A = exact f16 hi/lo split, B = single RTN f16 plane,
//  2-pass MFMA (absmax 0.03125, passed in R9/R10).
//  B LDS rows 80B stride; A rows 128B XOR-swizzled. 18.4KB/buffer dbuf,
//  launch_bounds(256,3). Fused grouping scan + XCD-pinned layers.

#define HDIM 1024
#define LNUM 16
#define BTOT 4096

constexpr int BM = 64, BN = 128, BK = 32;
constexpr int NT = HDIM / BK;   // 32 K-steps
constexpr int MSLOTS = 8;       // m-slots per layer in grid (strip-mined past)

constexpr int AROW = 128;       // A row: [32 hi f16 | 32 lo f16], XOR 8B cells
constexpr int BROW = 80;        // B row: 64B payload (32 hi f16) + 16B pad
constexpr int AOFF = 0;         // A tile: 64*128  = 8192 B
constexpr int BOFF = 8192;      // B tile: 128*80 = 10240 B
constexpr int BUFSZ = 8192 + 128 * 80;   // 18432 B per buffer

typedef __attribute__((ext_vector_type(4))) float floatx4;
typedef __attribute__((ext_vector_type(2))) __fp16 cvt16x2;   // cvt_pkrtz result
typedef __attribute__((ext_vector_type(8))) _Float16 f16x8;   // MFMA fragment
typedef __attribute__((ext_vector_type(2))) unsigned int uintx2;

// Exact split: v = hi + lo with hi,lo f16 (hi RTZ, lo catches residual).
__device__ __forceinline__ void split4(floatx4 v, uintx2& hw, uintx2& lw) {
    cvt16x2 h01 = __builtin_amdgcn_cvt_pkrtz(v[0], v[1]);
    cvt16x2 h23 = __builtin_amdgcn_cvt_pkrtz(v[2], v[3]);
    cvt16x2 l01 = __builtin_amdgcn_cvt_pkrtz(v[0] - (float)h01[0],
                                             v[1] - (float)h01[1]);
    cvt16x2 l23 = __builtin_amdgcn_cvt_pkrtz(v[2] - (float)h23[0],
                                             v[3] - (float)h23[1]);
    hw[0] = __builtin_bit_cast(unsigned int, h01);
    hw[1] = __builtin_bit_cast(unsigned int, h23);
    lw[0] = __builtin_bit_cast(unsigned int, l01);
    lw[1] = __builtin_bit_cast(unsigned int, l23);
}

// Round-to-nearest f32x4 -> packed f16x4 (single-plane B operand).
__device__ __forceinline__ uintx2 cvt4_rtn(floatx4 v) {
    _Float16 h0 = (_Float16)v[0], h1 = (_Float16)v[1];
    _Float16 h2 = (_Float16)v[2], h3 = (_Float16)v[3];
    uintx2 r;
    r[0] = (unsigned)__builtin_bit_cast(unsigned short, h0)
         | ((unsigned)__builtin_bit_cast(unsigned short, h1) << 16);
    r[1] = (unsigned)__builtin_bit_cast(unsigned short, h2)
         | ((unsigned)__builtin_bit_cast(unsigned short, h3) << 16);
    return r;
}

__global__ __launch_bounds__(256, 3) void fused_grouped_mfma_kernel(
    const float* __restrict__ z,
    const int* __restrict__ layer_ids,
    const float* __restrict__ weight,
    const float* __restrict__ bias,
    float* __restrict__ out) {

    // Grid: 1024 blocks = 8 XCD x {2 layer-halves x 8 m-slots x 8 n-blocks}.
    const int bid  = blockIdx.x;
    const int xcd  = bid & 7;
    const int slot = bid >> 3;                 // 0..127
    const int l    = xcd + ((slot >> 6) << 3); // 0..15
    const int rem  = slot & 63;
    const int my   = rem >> 3;                 // m-slot 0..7
    const int nx   = rem & 7;                  // n-block 0..7
    const int n0   = nx * BN;

    const int tid  = threadIdx.x;
    const int lane = tid & 63;
    const int w    = tid >> 6;                 // wave 0..3
    const int wm   = w & 1;                    // wave m-slot (rows wm*32..+31)
    const int wn   = w >> 1;                   // wave n-slot (cols wn*64..+63)

    __shared__ __align__(16) unsigned char sm[2][BUFSZ];
    __shared__ int permTile[BM];
    __shared__ int waveSums[4];

    // ---- fused grouping scan (rank of each matching b among layer-l rows) ----
    const int4* lid4 = (const int4*)layer_ids;
    unsigned mask = 0;
#pragma unroll
    for (int q = 0; q < 4; ++q) {
        int4 v = lid4[tid * 4 + q];
        mask |= (unsigned)(v.x == l) << (4 * q)
             |  (unsigned)(v.y == l) << (4 * q + 1)
             |  (unsigned)(v.z == l) << (4 * q + 2)
             |  (unsigned)(v.w == l) << (4 * q + 3);
    }
    const int ct = __popc(mask);
    int x = ct;                                // wave-inclusive scan of ct
#pragma unroll
    for (int o = 1; o < 64; o <<= 1) {
        int v = __shfl_up(x, o);
        if (lane >= o) x += v;
    }
    if (lane == 63) waveSums[w] = x;
    __syncthreads();
    int waveBase = 0, cnt = 0;
#pragma unroll
    for (int w2 = 0; w2 < 4; ++w2) {
        int s = waveSums[w2];
        if (w2 < w) waveBase += s;
        cnt += s;
    }
    const int et = waveBase + x - ct;          // exclusive rank of 1st match

    // ---- staging / fragment maps ----
    const int kq  = tid & 7;                   // 16B f32 chunk within 32-k slab
    const int rb  = tid >> 3;                  // staging row 0..31 (+32p)
    const int swz = (rb & 7) << 1;             // A 8B-cell XOR swizzle
    const int wA_hi = AOFF + rb * AROW + ((kq ^ swz) << 3);
    const int wA_lo = AOFF + rb * AROW + (((8 + kq) ^ swz) << 3);
    const int wB    = BOFF + rb * BROW + (kq << 3);

    const int lr = lane & 15;
    const int ks = lane >> 4;
    const int rdA_hi = AOFF + (wm * 32 + lr) * AROW + ((ks ^ (lr & 7)) << 4);
    const int rdA_lo = AOFF + (wm * 32 + lr) * AROW + (((4 + ks) ^ (lr & 7)) << 4);
    const int rdB    = BOFF + (wn * 64 + lr) * BROW + (ks << 4);

    const float* wBase = weight + (size_t)l * HDIM * HDIM;
    const int colBase = n0 + wn * 64 + lr;
    float bb[4];
#pragma unroll
    for (int j = 0; j < 4; ++j) bb[j] = bias[l * HDIM + colBase + j * 16];

    // ---- strip-mine m0 (single iteration for cnt <= 512, the normal case) ----
    for (int m0 = my * BM; m0 < cnt; m0 += MSLOTS * BM) {
        __syncthreads();                       // permTile / LDS reuse guard
        {
            unsigned m2 = mask;
            int r = et;
            while (m2) {
                int p = __ffs(m2) - 1;
                m2 &= m2 - 1;
                unsigned rr = (unsigned)(r - m0);
                if (rr < (unsigned)BM) permTile[rr] = tid * 16 + p;
                ++r;
            }
        }
        __syncthreads();

        const float* aPtr[2];
        const float* bPtr[4];
#pragma unroll
        for (int p = 0; p < 2; ++p) {
            int gm = rb + 32 * p;              // tile-local row
            if (gm > cnt - 1 - m0) gm = cnt - 1 - m0;   // clamp (stores guarded)
            aPtr[p] = z + (size_t)permTile[gm] * HDIM + kq * 4;
        }
#pragma unroll
        for (int p = 0; p < 4; ++p)
            bPtr[p] = wBase + (size_t)(n0 + rb + 32 * p) * HDIM + kq * 4;

        floatx4 acc[2][4] = {};
        floatx4 av[2], bv[4];                  // single prefetch reg set

        auto loadT = [&](int k0) {
#pragma unroll
            for (int p = 0; p < 2; ++p) av[p] = *(const floatx4*)(aPtr[p] + k0);
#pragma unroll
            for (int p = 0; p < 4; ++p) bv[p] = *(const floatx4*)(bPtr[p] + k0);
        };

        auto stageT = [&](unsigned char* buf) {
            uintx2 hw, lw;
#pragma unroll
            for (int p = 0; p < 2; ++p) {
                split4(av[p], hw, lw);
                *(uintx2*)(buf + wA_hi + p * 32 * AROW) = hw;
                *(uintx2*)(buf + wA_lo + p * 32 * AROW) = lw;
            }
#pragma unroll
            for (int p = 0; p < 4; ++p)
                *(uintx2*)(buf + wB + p * 32 * BROW) = cvt4_rtn(bv[p]);
        };

        auto compute = [&](const unsigned char* buf) {
            f16x8 ah[2], al[2], bh[4];
#pragma unroll
            for (int i = 0; i < 2; ++i) {
                ah[i] = *(const f16x8*)(buf + rdA_hi + i * 16 * AROW);
                al[i] = *(const f16x8*)(buf + rdA_lo + i * 16 * AROW);
            }
#pragma unroll
            for (int j = 0; j < 4; ++j)
                bh[j] = *(const f16x8*)(buf + rdB + j * 16 * BROW);
#pragma unroll
            for (int i = 0; i < 2; ++i)
#pragma unroll
                for (int j = 0; j < 4; ++j) {
                    acc[i][j] = __builtin_amdgcn_mfma_f32_16x16x32_f16(
                        ah[i], bh[j], acc[i][j], 0, 0, 0);
                    acc[i][j] = __builtin_amdgcn_mfma_f32_16x16x32_f16(
                        al[i], bh[j], acc[i][j], 0, 0, 0);
                }
        };

        // Prologue: L(0); S(0)->buf0 (one vmcnt stall, once); L(1); barrier.
        loadT(0);
        stageT(sm[0]);
        loadT(BK);
        __syncthreads();

        // Steady state per step t:
        //   stage(t+1)  -- regs loaded one full iteration ago
        //   load(t+2)   -- reuse regs right after ds_write consumed them
        //   compute(t)  -- reads buf staged last iteration
        //   barrier
#pragma unroll 1
        for (int t2 = 0; t2 < NT; t2 += 2) {
            stageT(sm[1]);                          // step t2+1 (t2+1 <= NT-1)
            if (t2 + 2 < NT) loadT((t2 + 2) * BK);
            compute(sm[0]);                         // step t2
            __syncthreads();

            if (t2 + 2 < NT) stageT(sm[0]);         // step t2+2
            if (t2 + 3 < NT) loadT((t2 + 3) * BK);
            compute(sm[1]);                         // step t2+1
            __syncthreads();
        }

        // Epilogue: C/D layout col=lane&15, row=(lane>>4)*4+reg (m89-verified).
        const int rq = lane >> 4;
#pragma unroll
        for (int i = 0; i < 2; ++i) {
#pragma unroll
            for (int v = 0; v < 4; ++v) {
                int gm = wm * 32 + i * 16 + rq * 4 + v;   // tile-local row
                if (m0 + gm < cnt) {
                    float* o = out + (size_t)permTile[gm] * HDIM + colBase;
#pragma unroll
                    for (int j = 0; j < 4; ++j) o[j * 16] = acc[i][j][v] + bb[j];
                }
            }
        }
    }
}

extern "C" void kernel_launch(void* const* d_in, const int* in_sizes, int n_in,
                              void* d_out, int out_size, void* d_ws, size_t ws_size,
                              hipStream_t stream) {
    // Order-proof pointer resolution (sizes disambiguate).
    const float* z = nullptr;
    const int* layer_ids = nullptr;
    const float* weight = nullptr;
    const float* bias = nullptr;
    for (int i = 0; i < n_in; ++i) {
        switch (in_sizes[i]) {
            case BTOT * HDIM:        z = (const float*)d_in[i]; break;
            case BTOT:               layer_ids = (const int*)d_in[i]; break;
            case LNUM * HDIM * HDIM: weight = (const float*)d_in[i]; break;
            case LNUM * HDIM:        bias = (const float*)d_in[i]; break;
        }
    }
    float* out = (float*)d_out;

    // Single dispatch: 8 XCD x 2 layer-halves x 8 m-slots x 8 n-blocks = 1024.
    fused_grouped_mfma_kernel<<<dim3(1024), 256, 0, stream>>>(
        z, layer_ids, weight, bias, out);
}